// Round 7
// baseline (348.459 us; speedup 1.0000x reference)
//
#include <hip/hip_runtime.h>
#include <stdint.h>

#define B_   2
#define S_   2048
#define D_   2048
#define QH_  32
#define KVH_ 8
#define HD_  64

typedef short  short8  __attribute__((ext_vector_type(8)));
typedef float  floatx4 __attribute__((ext_vector_type(4)));

__device__ __forceinline__ ushort f2b(float f) {
  union { float f; uint32_t u; } c; c.f = f;
  uint32_t u = c.u;
  return (ushort)((u + 0x7FFFu + ((u >> 16) & 1u)) >> 16);
}

__device__ __forceinline__ uint32_t fbits(float f) {
  union { float f; uint32_t u; } c; c.f = f;
  return c.u;
}

__device__ __forceinline__ short8 mk8(uint32_t a, uint32_t b, uint32_t c, uint32_t d) {
  union { uint4 u; short8 s; } v; v.u = (uint4){a, b, c, d}; return v.s;
}

// packed bf16 convert: lo = bf16(a), hi = bf16(b).
__device__ __forceinline__ uint32_t cvtpk(float a, float b) {
  uint32_t r;
  asm("v_cvt_pk_bf16_f32 %0, %1, %2" : "=v"(r) : "v"(a), "v"(b));
  return r;
}

// async global->LDS DMA, 16B per lane. LDS dest = wave-uniform base + lane*16.
__device__ __forceinline__ void dma16(const void* g, void* l) {
  __builtin_amdgcn_global_load_lds(
      (const __attribute__((address_space(1))) uint32_t*)(uintptr_t)g,
      (__attribute__((address_space(3))) uint32_t*)(uintptr_t)l, 16, 0, 0);
}

#define QSCALE 0.18033688f   // 1/sqrt(64) * log2(e)

// ---------------- elementwise converts ----------------

__global__ __launch_bounds__(256) void conv_x_kernel(const float* __restrict__ X,
                                                     ushort* __restrict__ Xb) {
  size_t i = ((size_t)blockIdx.x * 256 + threadIdx.x) * 4;
  float4 v = *(const float4*)(X + i);
  ushort4 o;
  o.x = f2b(v.x); o.y = f2b(v.y); o.z = f2b(v.z); o.w = f2b(v.w);
  *(ushort4*)(Xb + i) = o;
}

// Batched transpose+convert: z selects {Wq, Wk, Wv, Wo}. W [K=2048][N] -> Wt [N][K] bf16.
__global__ void tconv_all_kernel(const float* __restrict__ Wq, const float* __restrict__ Wk,
                                 const float* __restrict__ Wv, const float* __restrict__ Wo,
                                 ushort* __restrict__ wqkv, ushort* __restrict__ wo) {
  __shared__ float tile[32][33];
  int z = blockIdx.z;
  const float* W; ushort* Wt; int N;
  if (z == 0)      { W = Wq; Wt = wqkv;                        N = 2048; }
  else if (z == 1) { W = Wk; Wt = wqkv + (size_t)2048 * 2048;  N = 512;  }
  else if (z == 2) { W = Wv; Wt = wqkv + (size_t)2560 * 2048;  N = 512;  }
  else             { W = Wo; Wt = wo;                          N = 2048; }
  int bx = blockIdx.x, by = blockIdx.y;
  if (bx * 32 >= N) return;
  int tx = threadIdx.x, ty = threadIdx.y;
#pragma unroll
  for (int i = 0; i < 32; i += 8)
    tile[ty + i][tx] = W[(size_t)(by * 32 + ty + i) * N + bx * 32 + tx];
  __syncthreads();
#pragma unroll
  for (int i = 0; i < 32; i += 8)
    Wt[(size_t)(bx * 32 + ty + i) * 2048 + by * 32 + tx] = f2b(tile[tx][ty + i]);
}

// ---------------- fused QKV GEMM (2-phase 128x128) + bias + RoPE ----------
// r6 structure; __launch_bounds__(256, 5) caps VGPR at 102 to restore the
// cross-block occupancy the fused epilogue cost in r6 (VGPR 104 -> 16% occ).
// 5 blocks/CU is also the 160KB LDS limit. Main loop needs ~90 VGPR; the
// epilogue absorbs the squeeze.
// Q/K head dim stored PERMUTED: d' = l16*4 + ni (true d = ni*16 + l16).
// V path writes Vt [bb*8+h][64 dt][2048 pos-perm] directly (vpack fused).

__global__ __launch_bounds__(256, 5) void gemm_qkv_kernel(
    const ushort* __restrict__ A, const ushort* __restrict__ Bt,
    const float* __restrict__ bq, const float* __restrict__ bk,
    const float* __restrict__ bv, const float2* __restrict__ F2,
    ushort* __restrict__ qb, ushort* __restrict__ kb, ushort* __restrict__ vt) {
  const int K = 2048;
  __shared__ ushort sA[2][128 * 32];
  __shared__ ushort sB[2][128 * 32];
  const int tid  = threadIdx.x;
  const int bm   = blockIdx.y, bn = blockIdx.x;
  const int wave = tid >> 6, lane = tid & 63;
  const int quad = lane >> 4, l16 = lane & 15;
  const int wm   = (wave >> 1) * 64, wn = (wave & 1) * 64;

  const ushort* Ab = A  + (size_t)(bm * 128) * K;
  const ushort* Bb = Bt + (size_t)(bn * 128) * K;

  const int gr = lane >> 2;
  const int gu = (lane & 3) * 8;

  floatx4 acc[4][4];
#pragma unroll
  for (int i = 0; i < 4; i++)
#pragma unroll
    for (int j = 0; j < 4; j++) acc[i][j] = (floatx4){0.f, 0.f, 0.f, 0.f};

#pragma unroll
  for (int j = 0; j < 2; j++) {
    int row = j * 64 + wave * 16 + gr;
    dma16(Ab + (size_t)row * K + gu, &sA[0][j * 2048 + wave * 512]);
    dma16(Bb + (size_t)row * K + gu, &sB[0][j * 2048 + wave * 512]);
  }

  int cur = 0;
  for (int k0 = 0; k0 < K; k0 += 32) {
    __syncthreads();
    if (k0 + 32 < K) {
      int nxt = cur ^ 1;
#pragma unroll
      for (int j = 0; j < 2; j++) {
        int row = j * 64 + wave * 16 + gr;
        dma16(Ab + (size_t)row * K + k0 + 32 + gu, &sA[nxt][j * 2048 + wave * 512]);
        dma16(Bb + (size_t)row * K + k0 + 32 + gu, &sB[nxt][j * 2048 + wave * 512]);
      }
    }
    short8 af[4], bf[4];
#pragma unroll
    for (int mi = 0; mi < 4; mi++)
      af[mi] = *(const short8*)&sA[cur][(wm + mi * 16 + l16) * 32 + quad * 8];
#pragma unroll
    for (int ni = 0; ni < 4; ni++)
      bf[ni] = *(const short8*)&sB[cur][(wn + ni * 16 + l16) * 32 + quad * 8];
#pragma unroll
    for (int mi = 0; mi < 4; mi++)
#pragma unroll
      for (int ni = 0; ni < 4; ni++)
        acc[mi][ni] = __builtin_amdgcn_mfma_f32_16x16x32_bf16(
            af[mi], bf[ni], acc[mi][ni], 0, 0, 0);
    cur ^= 1;
  }

  // ---- fused epilogue ----
  const int isQ = (bn < 16);
  const int isV = (bn >= 20);
  const int hh  = wn >> 6;
  const float sySign = (l16 & 1) ? 1.f : -1.f;

  const float* bsrc = isQ ? bq : (isV ? bv : bk);
  const int    boff = isQ ? 0  : (isV ? 2560 : 2048);

  float bvv[4];
#pragma unroll
  for (int ni = 0; ni < 4; ni++)
    bvv[ni] = bsrc[bn * 128 + wn + ni * 16 + l16 - boff];

  if (!isV) {
    ushort* dst = isQ ? qb : kb;
    const int NH    = isQ ? QH_ : KVH_;
    const int hbase = isQ ? (bn * 2 + hh) : ((bn - 16) * 2 + hh);
#pragma unroll
    for (int mi = 0; mi < 4; mi++) {
#pragma unroll
      for (int r = 0; r < 4; r++) {
        int row = bm * 128 + wm + mi * 16 + quad * 4 + r;
        int s = row & 2047, bb = row >> 11;
        size_t base = (((size_t)bb * NH + hbase) * S_ + s) * HD_ + l16 * 4;
        float o[4];
#pragma unroll
        for (int ni = 0; ni < 4; ni++) {
          float xv = acc[mi][ni][r] + bvv[ni];
          float2 cs = F2[s * 32 + ni * 8 + (l16 >> 1)];
          float pp = __shfl_xor(xv, 1);
          float oo = fmaf(pp * sySign, cs.y, xv * cs.x);
          if (isQ) oo *= QSCALE;
          o[ni] = oo;
        }
        ushort4 pk;
        pk.x = f2b(o[0]); pk.y = f2b(o[1]); pk.z = f2b(o[2]); pk.w = f2b(o[3]);
        *(ushort4*)&dst[base] = pk;
      }
    }
  } else {
    // V: write directly into Vt [bb*8+h][64 dt][2048 pos-perm] (vpack fused).
    const int h = (bn - 20) * 2 + hh;
#pragma unroll
    for (int mi = 0; mi < 4; mi++) {
      int row0 = bm * 128 + wm + mi * 16 + quad * 4;
      int bb   = row0 >> 11;
      int posb = ((row0 & 2047) & ~63) + (mi & 2) * 16 + quad * 8 + (mi & 1) * 4;
#pragma unroll
      for (int ni = 0; ni < 4; ni++) {
        int dt = ni * 16 + l16;
        ushort4 st;
        st.x = f2b(acc[mi][ni][0] + bvv[ni]);
        st.y = f2b(acc[mi][ni][1] + bvv[ni]);
        st.z = f2b(acc[mi][ni][2] + bvv[ni]);
        st.w = f2b(acc[mi][ni][3] + bvv[ni]);
        *(ushort4*)&vt[(((size_t)bb * 8 + h) * 64 + dt) * (size_t)S_ + posb] = st;
      }
    }
  }
}

// ---------------- GEMM: C[M][N] = A @ Bt^T + bias (fp32 out) ----------------
// XCD-aware bijective block swizzle: grid 512 blocks (%8==0); each XCD gets
// 4 contiguous bm panels (2MB ob slice, L2-resident, 16x reuse).

__global__ __launch_bounds__(256) void gemm_bt_kernel(
    const ushort* __restrict__ A, const ushort* __restrict__ Bt,
    const float* __restrict__ bias, float* __restrict__ C,
    int M, int N, int K) {
  __shared__ ushort sA[2][128 * 32];
  __shared__ ushort sB[2][128 * 32];
  const int tid  = threadIdx.x;
  const int wg   = blockIdx.y * gridDim.x + blockIdx.x;
  const int id   = (wg & 7) * 64 + (wg >> 3);     // bijective, 512 blocks
  const int bm   = id >> 4, bn = id & 15;
  const int wave = tid >> 6, lane = tid & 63;
  const int quad = lane >> 4, l16 = lane & 15;
  const int wm   = (wave >> 1) * 64, wn = (wave & 1) * 64;

  const ushort* Ab = A  + (size_t)(bm * 128) * K;
  const ushort* Bb = Bt + (size_t)(bn * 128) * K;

  const int gr = lane >> 2;
  const int gu = (lane & 3) * 8;

  floatx4 acc[4][4];
#pragma unroll
  for (int i = 0; i < 4; i++)
#pragma unroll
    for (int j = 0; j < 4; j++) acc[i][j] = (floatx4){0.f, 0.f, 0.f, 0.f};

#pragma unroll
  for (int j = 0; j < 2; j++) {
    int row = j * 64 + wave * 16 + gr;
    dma16(Ab + (size_t)row * K + gu, &sA[0][j * 2048 + wave * 512]);
    dma16(Bb + (size_t)row * K + gu, &sB[0][j * 2048 + wave * 512]);
  }

  int cur = 0;
  for (int k0 = 0; k0 < K; k0 += 32) {
    __syncthreads();
    if (k0 + 32 < K) {
      int nxt = cur ^ 1;
#pragma unroll
      for (int j = 0; j < 2; j++) {
        int row = j * 64 + wave * 16 + gr;
        dma16(Ab + (size_t)row * K + k0 + 32 + gu, &sA[nxt][j * 2048 + wave * 512]);
        dma16(Bb + (size_t)row * K + k0 + 32 + gu, &sB[nxt][j * 2048 + wave * 512]);
      }
    }
    short8 af[4], bf[4];
#pragma unroll
    for (int mi = 0; mi < 4; mi++)
      af[mi] = *(const short8*)&sA[cur][(wm + mi * 16 + l16) * 32 + quad * 8];
#pragma unroll
    for (int ni = 0; ni < 4; ni++)
      bf[ni] = *(const short8*)&sB[cur][(wn + ni * 16 + l16) * 32 + quad * 8];
#pragma unroll
    for (int mi = 0; mi < 4; mi++)
#pragma unroll
      for (int ni = 0; ni < 4; ni++)
        acc[mi][ni] = __builtin_amdgcn_mfma_f32_16x16x32_bf16(
            af[mi], bf[ni], acc[mi][ni], 0, 0, 0);
    cur ^= 1;
  }

#pragma unroll
  for (int mi = 0; mi < 4; mi++) {
#pragma unroll
    for (int ni = 0; ni < 4; ni++) {
      int col  = bn * 128 + wn + ni * 16 + l16;
      float bv = bias[col];
#pragma unroll
      for (int r = 0; r < 4; r++) {
        int row = bm * 128 + wm + mi * 16 + quad * 4 + r;
        C[(size_t)row * N + col] = acc[mi][ni][r] + bv;
      }
    }
  }
}

// ---------------- Flash attention (register P, no LDS round-trip) ----------
// grid flat 512 blocks, block 512 (8 waves), 2 blocks/CU (4 waves/SIMD).
// KVBLK=128 (r7): halves barrier/drain events (16 iters). kBuf 128x64,
// vBuf 64x128, 64KB/block dbuf.
// Staging swizzle (both-sides): K rows wave*16+j*8+dr, d-chunk src
// (lane&7)^(dr&7) [row&7 == dr&7]; V d-rows wave*8+j*4+(lane>>4), kv-chunk
// src (lane&15)^(d&7). Reads XOR with swz=l16&7 recover natural chunks.
// Block-id remap clusters the 32 blocks sharing one (b,kvh) K/V per XCD.

__global__ __launch_bounds__(512, 4) void attn_kernel(
    const ushort* __restrict__ Q, const ushort* __restrict__ K,
    const ushort* __restrict__ Vt, ushort* __restrict__ O) {
  const int id  = blockIdx.x + 8 * (blockIdx.y + 32 * blockIdx.z);
  const int kvh = id & 7;
  const int qt  = (id >> 3) & 7;
  const int qh  = kvh * 4 + ((id >> 6) & 3);
  const int b   = id >> 8;
  const int tid = threadIdx.x;
  const int wave = tid >> 6, lane = tid & 63;
  const int quad = lane >> 4, l16 = lane & 15;

  __shared__ ushort kBuf[2][128 * 64];   // 32 KB
  __shared__ ushort vBuf[2][64 * 128];   // 32 KB

  const ushort* Qh = Q  + ((size_t)(b * QH_ + qh)) * S_ * HD_;
  const ushort* Kh = K  + ((size_t)(b * KVH_ + kvh)) * S_ * HD_;
  const ushort* Vh = Vt + ((size_t)(b * KVH_ + kvh)) * HD_ * S_;

  const int dr  = lane >> 3;
  const int du  = (lane & 7) ^ (dr & 7);
  const size_t kOff0 = (size_t)(wave * 16 + 0 + dr) * 64 + du * 8;
  const size_t kOff1 = (size_t)(wave * 16 + 8 + dr) * 64 + du * 8;
  const int vd0 = wave * 8 + 0 + (lane >> 4);
  const int vd1 = wave * 8 + 4 + (lane >> 4);
  const size_t vOff0 = (size_t)vd0 * S_ + (size_t)((((lane & 15) ^ (vd0 & 7))) * 8);
  const size_t vOff1 = (size_t)vd1 * S_ + (size_t)((((lane & 15) ^ (vd1 & 7))) * 8);
  const int swz = l16 & 7;

  const int q0 = qt * 256 + wave * 32;
  short8 aq[2][2];
#pragma unroll
  for (int m = 0; m < 2; m++)
#pragma unroll
    for (int s2 = 0; s2 < 2; s2++)
      aq[m][s2] = *(const short8*)(Qh + (size_t)(q0 + m * 16 + l16) * HD_ + s2 * 32 + quad * 8);

  floatx4 oacc[2][4];
#pragma unroll
  for (int m = 0; m < 2; m++)
#pragma unroll
    for (int t = 0; t < 4; t++) oacc[m][t] = (floatx4){0.f, 0.f, 0.f, 0.f};
  float ls[2] = {0.f, 0.f};

  dma16(Kh + kOff0, &kBuf[0][wave * 1024]);
  dma16(Kh + kOff1, &kBuf[0][wave * 1024 + 512]);
  dma16(Vh + vOff0, &vBuf[0][wave * 1024]);
  dma16(Vh + vOff1, &vBuf[0][wave * 1024 + 512]);

  int cur = 0;
  for (int kv0 = 0; kv0 < S_; kv0 += 128) {
    __syncthreads();
    if (kv0 + 128 < S_) {
      int nxt = cur ^ 1;
      dma16(Kh + (size_t)(kv0 + 128) * 64 + kOff0, &kBuf[nxt][wave * 1024]);
      dma16(Kh + (size_t)(kv0 + 128) * 64 + kOff1, &kBuf[nxt][wave * 1024 + 512]);
      dma16(Vh + (size_t)(kv0 + 128) + vOff0,      &vBuf[nxt][wave * 1024]);
      dma16(Vh + (size_t)(kv0 + 128) + vOff1,      &vBuf[nxt][wave * 1024 + 512]);
    }

#pragma unroll
    for (int u = 0; u < 4; u++) {
      uint32_t pk[2][4];   // [m][word]: PV A-fragment words
#pragma unroll
      for (int cc = 0; cc < 2; cc++) {
        const int c = u * 2 + cc;
        short8 kf0 = *(const short8*)&kBuf[cur][(c * 16 + l16) * 64 + ((quad ^ swz) * 8)];
        short8 kf1 = *(const short8*)&kBuf[cur][(c * 16 + l16) * 64 + (((4 + quad) ^ swz) * 8)];
#pragma unroll
        for (int m = 0; m < 2; m++) {
          floatx4 sc = (floatx4){0.f, 0.f, 0.f, 0.f};
          __builtin_amdgcn_s_setprio(1);
          sc = __builtin_amdgcn_mfma_f32_16x16x32_bf16(kf0, aq[m][0], sc, 0, 0, 0);
          sc = __builtin_amdgcn_mfma_f32_16x16x32_bf16(kf1, aq[m][1], sc, 0, 0, 0);
          __builtin_amdgcn_s_setprio(0);
          float p0 = __builtin_amdgcn_exp2f(sc[0]);
          float p1 = __builtin_amdgcn_exp2f(sc[1]);
          float p2 = __builtin_amdgcn_exp2f(sc[2]);
          float p3 = __builtin_amdgcn_exp2f(sc[3]);
          ls[m] += (p0 + p1) + (p2 + p3);
          pk[m][cc * 2 + 0] = cvtpk(p0, p1);
          pk[m][cc * 2 + 1] = cvtpk(p2, p3);
        }
      }
#pragma unroll
      for (int t = 0; t < 4; t++) {
        const int row = (t * 16 + l16) * 128;
        short8 vf = *(const short8*)&vBuf[cur][row + (((u * 4 + quad) ^ swz) * 8)];
        __builtin_amdgcn_s_setprio(1);
#pragma unroll
        for (int m = 0; m < 2; m++) {
          short8 ap = mk8(pk[m][0], pk[m][1], pk[m][2], pk[m][3]);
          oacc[m][t] = __builtin_amdgcn_mfma_f32_16x16x32_bf16(ap, vf, oacc[m][t], 0, 0, 0);
        }
        __builtin_amdgcn_s_setprio(0);
      }
    }
    cur ^= 1;
  }

#pragma unroll
  for (int m = 0; m < 2; m++) {
    ls[m] += __shfl_xor(ls[m], 16);
    ls[m] += __shfl_xor(ls[m], 32);
  }
#pragma unroll
  for (int m = 0; m < 2; m++) {
#pragma unroll
    for (int r = 0; r < 4; r++) {
      float l = __shfl(ls[m], (lane & 48) | (quad * 4 + r));
      float inv = 1.0f / l;
      int srow = q0 + m * 16 + quad * 4 + r;
      size_t base = ((size_t)b * S_ + srow) * (QH_ * HD_) + (size_t)qh * HD_;
#pragma unroll
      for (int t = 0; t < 4; t++)
        O[base + t * 16 + l16] = f2b(oacc[m][t][r] * inv);
    }
  }
}

// ---------------- launch ----------------

extern "C" void kernel_launch(void* const* d_in, const int* in_sizes, int n_in,
                              void* d_out, int out_size, void* d_ws, size_t ws_size,
                              hipStream_t stream) {
  const float* x  = (const float*)d_in[0];
  const float* fr = (const float*)d_in[1];
  const float* Wq = (const float*)d_in[2];
  const float* bq = (const float*)d_in[3];
  const float* Wk = (const float*)d_in[4];
  const float* bk = (const float*)d_in[5];
  const float* Wv = (const float*)d_in[6];
  const float* bv = (const float*)d_in[7];
  const float* Wo = (const float*)d_in[8];
  const float* bo = (const float*)d_in[9];
  float* out = (float*)d_out;
  char* ws = (char*)d_ws;

  ushort* xb    = (ushort*)(ws + 0);           // 16,777,216  x bf16 (reused as Ob)
  ushort* wqkv  = (ushort*)(ws + 16777216);    // 12,582,912
  ushort* wo    = (ushort*)(ws + 29360128);    //  8,388,608
  ushort* qb    = (ushort*)(ws + 37761024);    // 16,777,216  Q roped bf16 (perm d)
  ushort* kb    = (ushort*)(ws + 54538240);    //  4,194,304  K roped bf16 (perm d)
  ushort* vt    = (ushort*)(ws + 62926848);    //  4,194,304  V [d][s-perm] true-d
  ushort* ob    = xb;                          // alias: xb dead after gemm1

  conv_x_kernel<<<8192, 256, 0, stream>>>(x, xb);
  tconv_all_kernel<<<dim3(64, 64, 4), dim3(32, 8), 0, stream>>>(Wq, Wk, Wv, Wo, wqkv, wo);

  gemm_qkv_kernel<<<dim3(3072 / 128, 4096 / 128), 256, 0, stream>>>(
      xb, wqkv, bq, bk, bv, (const float2*)fr, qb, kb, vt);

  attn_kernel<<<dim3(8, 32, 2), 512, 0, stream>>>(qb, kb, vt, ob);

  gemm_bt_kernel<<<dim3(2048 / 128, 4096 / 128), 256, 0, stream>>>(
      ob, wo, bo, out, 4096, 2048, 2048);
}

// Round 8
// 302.643 us; speedup vs baseline: 1.1514x; 1.1514x over previous
//
#include <hip/hip_runtime.h>
#include <stdint.h>

#define B_   2
#define S_   2048
#define D_   2048
#define QH_  32
#define KVH_ 8
#define HD_  64

typedef short  short8  __attribute__((ext_vector_type(8)));
typedef float  floatx4 __attribute__((ext_vector_type(4)));

__device__ __forceinline__ ushort f2b(float f) {
  union { float f; uint32_t u; } c; c.f = f;
  uint32_t u = c.u;
  return (ushort)((u + 0x7FFFu + ((u >> 16) & 1u)) >> 16);
}

__device__ __forceinline__ uint32_t fbits(float f) {
  union { float f; uint32_t u; } c; c.f = f;
  return c.u;
}

__device__ __forceinline__ short8 mk8(uint32_t a, uint32_t b, uint32_t c, uint32_t d) {
  union { uint4 u; short8 s; } v; v.u = (uint4){a, b, c, d}; return v.s;
}

// packed bf16 convert: lo = bf16(a), hi = bf16(b).
__device__ __forceinline__ uint32_t cvtpk(float a, float b) {
  uint32_t r;
  asm("v_cvt_pk_bf16_f32 %0, %1, %2" : "=v"(r) : "v"(a), "v"(b));
  return r;
}

// async global->LDS DMA, 16B per lane. LDS dest = wave-uniform base + lane*16.
__device__ __forceinline__ void dma16(const void* g, void* l) {
  __builtin_amdgcn_global_load_lds(
      (const __attribute__((address_space(1))) uint32_t*)(uintptr_t)g,
      (__attribute__((address_space(3))) uint32_t*)(uintptr_t)l, 16, 0, 0);
}

#define QSCALE 0.18033688f   // 1/sqrt(64) * log2(e)

// ---------------- elementwise converts ----------------

__global__ __launch_bounds__(256) void conv_x_kernel(const float* __restrict__ X,
                                                     ushort* __restrict__ Xb) {
  size_t i = ((size_t)blockIdx.x * 256 + threadIdx.x) * 4;
  float4 v = *(const float4*)(X + i);
  ushort4 o;
  o.x = f2b(v.x); o.y = f2b(v.y); o.z = f2b(v.z); o.w = f2b(v.w);
  *(ushort4*)(Xb + i) = o;
}

// Batched transpose+convert: z selects {Wq, Wk, Wv, Wo}. W [K=2048][N] -> Wt [N][K] bf16.
__global__ void tconv_all_kernel(const float* __restrict__ Wq, const float* __restrict__ Wk,
                                 const float* __restrict__ Wv, const float* __restrict__ Wo,
                                 ushort* __restrict__ wqkv, ushort* __restrict__ wo) {
  __shared__ float tile[32][33];
  int z = blockIdx.z;
  const float* W; ushort* Wt; int N;
  if (z == 0)      { W = Wq; Wt = wqkv;                        N = 2048; }
  else if (z == 1) { W = Wk; Wt = wqkv + (size_t)2048 * 2048;  N = 512;  }
  else if (z == 2) { W = Wv; Wt = wqkv + (size_t)2560 * 2048;  N = 512;  }
  else             { W = Wo; Wt = wo;                          N = 2048; }
  int bx = blockIdx.x, by = blockIdx.y;
  if (bx * 32 >= N) return;
  int tx = threadIdx.x, ty = threadIdx.y;
#pragma unroll
  for (int i = 0; i < 32; i += 8)
    tile[ty + i][tx] = W[(size_t)(by * 32 + ty + i) * N + bx * 32 + tx];
  __syncthreads();
#pragma unroll
  for (int i = 0; i < 32; i += 8)
    Wt[(size_t)(bx * 32 + ty + i) * 2048 + by * 32 + tx] = f2b(tile[tx][ty + i]);
}

// ---------------- fused QKV GEMM, 8-phase 256x256 schedule (r5 verified) ----
// BM=BN=256, BK=64, 8 waves (2M x 4N), 512 threads, 128 KiB LDS dbuf.
// Epilogue fuses bias (direct bq/bk/bv) and vpack (V -> Vt directly).
// NOTE r7 lesson: do NOT add a min-waves __launch_bounds__ here — forcing
// occupancy spilled acc[] to scratch (VGPR 48, WRITE_SIZE 5x, 123 us).

__global__ __launch_bounds__(512, 2) void gemm_qkv_kernel(
    const ushort* __restrict__ A, const ushort* __restrict__ Bt,
    const float* __restrict__ bq, const float* __restrict__ bk,
    const float* __restrict__ bv, const float2* __restrict__ F2,
    ushort* __restrict__ qb, ushort* __restrict__ kb, ushort* __restrict__ vt) {
  __shared__ ushort sA[2][256 * 64];
  __shared__ ushort sB[2][256 * 64];
  const int tid  = threadIdx.x;
  const int bm   = blockIdx.y, bn = blockIdx.x;
  const int wave = tid >> 6, lane = tid & 63;
  const int quad = lane >> 4, l16 = lane & 15;
  const int wm2  = wave >> 2, wn4 = wave & 3;
  const int sw7  = l16 & 7;
  const int dr   = lane >> 3, du = (lane & 7) ^ dr;
  const int srow = wave * 8 + dr;
  const int lcol = (lane & 7) * 8;

  const ushort* Ab = A  + (size_t)(bm * 256) * 2048;
  const ushort* Bb = Bt + (size_t)(bn * 256) * 2048;

  floatx4 acc[8][4];
#pragma unroll
  for (int i = 0; i < 8; i++)
#pragma unroll
    for (int j = 0; j < 4; j++) acc[i][j] = (floatx4){0.f, 0.f, 0.f, 0.f};

  short8 af[4][2], bf[4][2];

#define STG_A(t, h) do {                                                      \
    dma16(Ab + (size_t)((h)*128 +      srow) * 2048 + (size_t)(t)*64 + du*8,  \
          &sA[(t)&1][((h)*128 +      srow) * 64 + lcol]);                     \
    dma16(Ab + (size_t)((h)*128 + 64 + srow) * 2048 + (size_t)(t)*64 + du*8,  \
          &sA[(t)&1][((h)*128 + 64 + srow) * 64 + lcol]);                     \
  } while (0)

#define STG_B(t, h) do {                                                      \
    dma16(Bb + (size_t)((h)*128 +      srow) * 2048 + (size_t)(t)*64 + du*8,  \
          &sB[(t)&1][((h)*128 +      srow) * 64 + lcol]);                     \
    dma16(Bb + (size_t)((h)*128 + 64 + srow) * 2048 + (size_t)(t)*64 + du*8,  \
          &sB[(t)&1][((h)*128 + 64 + srow) * 64 + lcol]);                     \
  } while (0)

#define LDA(Sb, mh) do {                                                      \
    _Pragma("unroll") for (int mi2 = 0; mi2 < 4; mi2++) {                     \
      const int rr = ((mh)*128 + wm2*64 + mi2*16 + l16) * 64;                 \
      af[mi2][0] = *(const short8*)&(Sb)[rr + (((quad    ) ^ sw7) * 8)];      \
      af[mi2][1] = *(const short8*)&(Sb)[rr + (((quad + 4) ^ sw7) * 8)];      \
    } } while (0)

#define LDB(Sb, nh) do {                                                      \
    _Pragma("unroll") for (int ni2 = 0; ni2 < 2; ni2++) {                     \
      const int rr = ((nh)*128 + wn4*32 + ni2*16 + l16) * 64;                 \
      bf[(nh)*2+ni2][0] = *(const short8*)&(Sb)[rr + (((quad    ) ^ sw7) * 8)]; \
      bf[(nh)*2+ni2][1] = *(const short8*)&(Sb)[rr + (((quad + 4) ^ sw7) * 8)]; \
    } } while (0)

#define MFMA_PH(mh, nh) do {                                                  \
    __builtin_amdgcn_s_setprio(1);                                           \
    _Pragma("unroll") for (int mi2 = 0; mi2 < 4; mi2++)                       \
    _Pragma("unroll") for (int ni2 = 0; ni2 < 2; ni2++)                       \
    _Pragma("unroll") for (int ks = 0; ks < 2; ks++)                          \
      acc[(mh)*4+mi2][(nh)*2+ni2] = __builtin_amdgcn_mfma_f32_16x16x32_bf16(  \
        af[mi2][ks], bf[(nh)*2+ni2][ks], acc[(mh)*4+mi2][(nh)*2+ni2], 0,0,0); \
    __builtin_amdgcn_s_setprio(0);                                            \
  } while (0)

#define PH_SYNC() do {                                                        \
    __builtin_amdgcn_sched_barrier(0);                                        \
    __builtin_amdgcn_s_barrier();                                             \
    asm volatile("s_waitcnt lgkmcnt(0)" ::: "memory");                        \
    __builtin_amdgcn_sched_barrier(0);                                        \
  } while (0)

#define PH_END() do {                                                         \
    __builtin_amdgcn_sched_barrier(0);                                        \
    __builtin_amdgcn_s_barrier();                                             \
    __builtin_amdgcn_sched_barrier(0);                                        \
  } while (0)

  // ---- prologue: tile0 full + tile1 {hA0, hB0, hB1} (order matters) ----
  STG_A(0, 0); STG_A(0, 1); STG_B(0, 0); STG_B(0, 1);
  STG_A(1, 0); STG_B(1, 0); STG_B(1, 1);
  asm volatile("s_waitcnt vmcnt(6)" ::: "memory");
  __builtin_amdgcn_s_barrier();

#pragma unroll 1
  for (int i = 0; i < 16; ++i) {
    const int t0 = 2 * i, t1 = 2 * i + 1;
    const bool more = (i < 15);
    const ushort* A0 = sA[0]; const ushort* B0 = sB[0];
    const ushort* A1 = sA[1]; const ushort* B1 = sB[1];

    // phase 1: read B0[nh0] + A0[mh0]; stage hA1(t1)
    LDB(B0, 0); LDA(A0, 0);
    STG_A(t1, 1);
    PH_SYNC(); MFMA_PH(0, 0); PH_END();

    // phase 2: read B0[nh1]; stage hA0(t0+2)
    LDB(B0, 1);
    if (more) STG_A(t0 + 2, 0);
    PH_SYNC(); MFMA_PH(0, 1); PH_END();

    // phase 3: read A0[mh1]; stage hB0(t0+2)
    LDA(A0, 1);
    if (more) STG_B(t0 + 2, 0);
    PH_SYNC(); MFMA_PH(1, 0); PH_END();

    // phase 4: stage hB1(t0+2); vmcnt -> tile t1 landed
    if (more) STG_B(t0 + 2, 1);
    PH_SYNC(); MFMA_PH(1, 1);
    if (more) asm volatile("s_waitcnt vmcnt(6)" ::: "memory");
    else      asm volatile("s_waitcnt vmcnt(0)" ::: "memory");
    PH_END();

    // phase 5: read B1[nh0] + A1[mh0]; stage hA1(t0+2)
    LDB(B1, 0); LDA(A1, 0);
    if (more) STG_A(t0 + 2, 1);
    PH_SYNC(); MFMA_PH(0, 0); PH_END();

    // phase 6: read B1[nh1]; stage hA0(t1+2)
    LDB(B1, 1);
    if (more) STG_A(t1 + 2, 0);
    PH_SYNC(); MFMA_PH(0, 1); PH_END();

    // phase 7: read A1[mh1]; stage hB0(t1+2)
    LDA(A1, 1);
    if (more) STG_B(t1 + 2, 0);
    PH_SYNC(); MFMA_PH(1, 0); PH_END();

    // phase 8: stage hB1(t1+2); vmcnt -> tile t0+2 landed
    if (more) STG_B(t1 + 2, 1);
    PH_SYNC(); MFMA_PH(1, 1);
    if (more) asm volatile("s_waitcnt vmcnt(6)" ::: "memory");
    PH_END();
  }

#undef STG_A
#undef STG_B
#undef LDA
#undef LDB
#undef MFMA_PH
#undef PH_SYNC
#undef PH_END

  // ---- fused epilogue (bias + RoPE + permuted-d packed stores; V->Vt) ----
  const int isQ = (bn < 8);
  const int isV = (bn >= 10);
  const float sySign = (l16 & 1) ? 1.f : -1.f;

  const float* bsrc = isQ ? bq : (isV ? bv : bk);
  const int    boff = isQ ? 0  : (isV ? 2560 : 2048);

  float bvv[4];
#pragma unroll
  for (int ni = 0; ni < 4; ni++)
    bvv[ni] = bsrc[bn * 256 + (ni >> 1) * 128 + wn4 * 32 + (ni & 1) * 16 + l16 - boff];

  if (!isV) {
    ushort* dst = isQ ? qb : kb;
    const int NH   = isQ ? QH_ : KVH_;
    const int hoff = isQ ? 0 : 8;
    const int dpb  = l16 * 4 + (wn4 & 1) * 2;
#pragma unroll
    for (int mi = 0; mi < 8; mi++) {
#pragma unroll
      for (int r = 0; r < 4; r++) {
        int row = bm * 256 + (mi >> 2) * 128 + wm2 * 64 + (mi & 3) * 16 + quad * 4 + r;
        int s = row & 2047, bb = row >> 11;
        float o[4];
#pragma unroll
        for (int ni = 0; ni < 4; ni++) {
          float xv = acc[mi][ni][r] + bvv[ni];
          float2 cs = F2[s * 32 + (wn4 & 1) * 16 + (ni & 1) * 8 + (l16 >> 1)];
          float pp = __shfl_xor(xv, 1);
          float oo = fmaf(pp * sySign, cs.y, xv * cs.x);
          if (isQ) oo *= QSCALE;
          o[ni] = oo;
        }
#pragma unroll
        for (int hh = 0; hh < 2; hh++) {
          int h = (bn - hoff) * 4 + hh * 2 + (wn4 >> 1);
          size_t base = (((size_t)bb * NH + h) * S_ + s) * HD_ + dpb;
          ushort2 st; st.x = f2b(o[hh * 2 + 0]); st.y = f2b(o[hh * 2 + 1]);
          *(ushort2*)&dst[base] = st;
        }
      }
    }
  } else {
    // V: write directly into Vt [bb*8+h][64 d][2048 pos] (vpack fused).
#pragma unroll
    for (int mi = 0; mi < 8; mi++) {
      int row0 = bm * 256 + (mi >> 2) * 128 + wm2 * 64 + (mi & 3) * 16 + quad * 4;
      int bb   = row0 >> 11;
      int posb = ((row0 & 2047) & ~63) + (mi & 2) * 16 + quad * 8 + (mi & 1) * 4;
#pragma unroll
      for (int ni = 0; ni < 4; ni++) {
        int h  = (bn - 10) * 4 + (ni >> 1) * 2 + (wn4 >> 1);
        int dt = (wn4 & 1) * 32 + (ni & 1) * 16 + l16;
        ushort4 st;
        st.x = f2b(acc[mi][ni][0] + bvv[ni]);
        st.y = f2b(acc[mi][ni][1] + bvv[ni]);
        st.z = f2b(acc[mi][ni][2] + bvv[ni]);
        st.w = f2b(acc[mi][ni][3] + bvv[ni]);
        *(ushort4*)&vt[(((size_t)bb * 8 + h) * 64 + dt) * (size_t)S_ + posb] = st;
      }
    }
  }
}

// ---------------- GEMM: C[M][N] = A @ Bt^T + bias (fp32 out) ----------------
// Linear block mapping: xcd = wg%8 = bn%8 naturally gives each XCD a fixed
// 2-column B slice (2MB, L2-resident, 32x reuse). Do NOT swizzle (r7 lesson:
// remapping gave each XCD all 8.4MB of B -> L2 thrash).

__global__ __launch_bounds__(256) void gemm_bt_kernel(
    const ushort* __restrict__ A, const ushort* __restrict__ Bt,
    const float* __restrict__ bias, float* __restrict__ C,
    int M, int N, int K) {
  __shared__ ushort sA[2][128 * 32];
  __shared__ ushort sB[2][128 * 32];
  const int tid  = threadIdx.x;
  const int bm   = blockIdx.y, bn = blockIdx.x;
  const int wave = tid >> 6, lane = tid & 63;
  const int quad = lane >> 4, l16 = lane & 15;
  const int wm   = (wave >> 1) * 64, wn = (wave & 1) * 64;

  const ushort* Ab = A  + (size_t)(bm * 128) * K;
  const ushort* Bb = Bt + (size_t)(bn * 128) * K;

  const int gr = lane >> 2;
  const int gu = (lane & 3) * 8;

  floatx4 acc[4][4];
#pragma unroll
  for (int i = 0; i < 4; i++)
#pragma unroll
    for (int j = 0; j < 4; j++) acc[i][j] = (floatx4){0.f, 0.f, 0.f, 0.f};

#pragma unroll
  for (int j = 0; j < 2; j++) {
    int row = j * 64 + wave * 16 + gr;
    dma16(Ab + (size_t)row * K + gu, &sA[0][j * 2048 + wave * 512]);
    dma16(Bb + (size_t)row * K + gu, &sB[0][j * 2048 + wave * 512]);
  }

  int cur = 0;
  for (int k0 = 0; k0 < K; k0 += 32) {
    __syncthreads();
    if (k0 + 32 < K) {
      int nxt = cur ^ 1;
#pragma unroll
      for (int j = 0; j < 2; j++) {
        int row = j * 64 + wave * 16 + gr;
        dma16(Ab + (size_t)row * K + k0 + 32 + gu, &sA[nxt][j * 2048 + wave * 512]);
        dma16(Bb + (size_t)row * K + k0 + 32 + gu, &sB[nxt][j * 2048 + wave * 512]);
      }
    }
    short8 af[4], bf[4];
#pragma unroll
    for (int mi = 0; mi < 4; mi++)
      af[mi] = *(const short8*)&sA[cur][(wm + mi * 16 + l16) * 32 + quad * 8];
#pragma unroll
    for (int ni = 0; ni < 4; ni++)
      bf[ni] = *(const short8*)&sB[cur][(wn + ni * 16 + l16) * 32 + quad * 8];
#pragma unroll
    for (int mi = 0; mi < 4; mi++)
#pragma unroll
      for (int ni = 0; ni < 4; ni++)
        acc[mi][ni] = __builtin_amdgcn_mfma_f32_16x16x32_bf16(
            af[mi], bf[ni], acc[mi][ni], 0, 0, 0);
    cur ^= 1;
  }

#pragma unroll
  for (int mi = 0; mi < 4; mi++) {
#pragma unroll
    for (int ni = 0; ni < 4; ni++) {
      int col  = bn * 128 + wn + ni * 16 + l16;
      float bv = bias[col];
#pragma unroll
      for (int r = 0; r < 4; r++) {
        int row = bm * 128 + wm + mi * 16 + quad * 4 + r;
        C[(size_t)row * N + col] = acc[mi][ni][r] + bv;
      }
    }
  }
}

// ---------------- Flash attention (register P, no LDS round-trip) ----------
// grid flat 512 blocks, block 512 (8 waves), 2 blocks/CU (4 waves/SIMD).
// Block-id remap clusters all 32 blocks sharing one (b,kvh)'s K/V onto one
// XCD: id = kvh + 8*qt + 64*g + 256*b.
// r8: 3-buffer ring + counted vmcnt (T3/T4). Tile i's loads are issued 2
// iterations before use (~1200cy cover vs ~600 before) so HBM-miss latency
// (~900cy) is hidden; vmcnt(2) at the barrier leaves tile i+1 in flight
// instead of draining to 0. FIFO accounting: entering iter i, in-flight =
// {tile i, tile i+1} (2 loads/wave each); vmcnt(2) drains exactly tile i.
// Peeled last iter drains with vmcnt(0). WAR safe: buf[(i+2)%3] was last
// read in iter i-1, and all waves passed the iter-i barrier after that.

__global__ __launch_bounds__(512, 4) void attn_kernel(
    const ushort* __restrict__ Q, const ushort* __restrict__ K,
    const ushort* __restrict__ Vt, ushort* __restrict__ O) {
  const int id  = blockIdx.x + 8 * (blockIdx.y + 32 * blockIdx.z);
  const int kvh = id & 7;
  const int qt  = (id >> 3) & 7;
  const int qh  = kvh * 4 + ((id >> 6) & 3);
  const int b   = id >> 8;
  const int tid = threadIdx.x;
  const int wave = tid >> 6, lane = tid & 63;
  const int quad = lane >> 4, l16 = lane & 15;

  __shared__ ushort kBuf[3][64 * 64];   // 24 KB
  __shared__ ushort vBuf[3][64 * 64];   // 24 KB

  const ushort* Qh = Q  + ((size_t)(b * QH_ + qh)) * S_ * HD_;
  const ushort* Kh = K  + ((size_t)(b * KVH_ + kvh)) * S_ * HD_;
  const ushort* Vh = Vt + ((size_t)(b * KVH_ + kvh)) * HD_ * S_;

  const int dr = lane >> 3;
  const int du = (lane & 7) ^ (dr & 7);
  const size_t kLaneOff = (size_t)(wave * 8 + dr) * 64 + du * 8;
  const size_t vLaneOff = (size_t)(wave * 8 + dr) * S_ + du * 8;
  const int swz = l16 & 7;

  const int q0 = qt * 256 + wave * 32;
  short8 aq[2][2];
#pragma unroll
  for (int m = 0; m < 2; m++)
#pragma unroll
    for (int s2 = 0; s2 < 2; s2++)
      aq[m][s2] = *(const short8*)(Qh + (size_t)(q0 + m * 16 + l16) * HD_ + s2 * 32 + quad * 8);

  floatx4 oacc[2][4];
#pragma unroll
  for (int m = 0; m < 2; m++)
#pragma unroll
    for (int t = 0; t < 4; t++) oacc[m][t] = (floatx4){0.f, 0.f, 0.f, 0.f};
  float ls[2] = {0.f, 0.f};

  // prologue: stage tiles 0 and 1 (2 dma16/wave each)
  dma16(Kh + kLaneOff, &kBuf[0][wave * 512]);
  dma16(Vh + vLaneOff, &vBuf[0][wave * 512]);
  dma16(Kh + (size_t)64 * 64 + kLaneOff, &kBuf[1][wave * 512]);
  dma16(Vh + 64 + vLaneOff,              &vBuf[1][wave * 512]);

#define ATTN_TILE(KB, VB)                                                     \
  do {                                                                        \
    _Pragma("unroll")                                                         \
    for (int u = 0; u < 2; u++) {                                             \
      uint32_t pk[2][4];                                                      \
      _Pragma("unroll")                                                       \
      for (int cc = 0; cc < 2; cc++) {                                        \
        const int c = u * 2 + cc;                                             \
        short8 kf0 = *(const short8*)&(KB)[(c * 16 + l16) * 64 + ((quad ^ swz) * 8)];        \
        short8 kf1 = *(const short8*)&(KB)[(c * 16 + l16) * 64 + (((4 + quad) ^ swz) * 8)];  \
        _Pragma("unroll")                                                     \
        for (int m = 0; m < 2; m++) {                                         \
          floatx4 sc = (floatx4){0.f, 0.f, 0.f, 0.f};                         \
          __builtin_amdgcn_s_setprio(1);                                      \
          sc = __builtin_amdgcn_mfma_f32_16x16x32_bf16(kf0, aq[m][0], sc, 0, 0, 0); \
          sc = __builtin_amdgcn_mfma_f32_16x16x32_bf16(kf1, aq[m][1], sc, 0, 0, 0); \
          __builtin_amdgcn_s_setprio(0);                                      \
          float p0 = __builtin_amdgcn_exp2f(sc[0]);                           \
          float p1 = __builtin_amdgcn_exp2f(sc[1]);                           \
          float p2 = __builtin_amdgcn_exp2f(sc[2]);                           \
          float p3 = __builtin_amdgcn_exp2f(sc[3]);                           \
          ls[m] += (p0 + p1) + (p2 + p3);                                     \
          pk[m][cc * 2 + 0] = cvtpk(p0, p1);                                  \
          pk[m][cc * 2 + 1] = cvtpk(p2, p3);                                  \
        }                                                                     \
      }                                                                       \
      _Pragma("unroll")                                                       \
      for (int t = 0; t < 4; t++) {                                           \
        const int row = (t * 16 + l16) * 64;                                  \
        short8 vf = *(const short8*)&(VB)[row + (((u * 4 + quad) ^ swz) * 8)]; \
        __builtin_amdgcn_s_setprio(1);                                        \
        _Pragma("unroll")                                                     \
        for (int m = 0; m < 2; m++) {                                         \
          short8 ap = mk8(pk[m][0], pk[m][1], pk[m][2], pk[m][3]);            \
          oacc[m][t] = __builtin_amdgcn_mfma_f32_16x16x32_bf16(ap, vf, oacc[m][t], 0, 0, 0); \
        }                                                                     \
        __builtin_amdgcn_s_setprio(0);                                        \
      }                                                                       \
    }                                                                         \
  } while (0)

  int cur = 0, stg = 2;
#pragma unroll 1
  for (int i = 0; i < 31; ++i) {
    // drain tile i (leave tile i+1 in flight), then sync
    __builtin_amdgcn_sched_barrier(0);
    asm volatile("s_waitcnt vmcnt(2)" ::: "memory");
    __builtin_amdgcn_s_barrier();
    __builtin_amdgcn_sched_barrier(0);

    if (i <= 29) {
      size_t kv2 = (size_t)(i + 2) * 64;
      dma16(Kh + kv2 * 64 + kLaneOff, &kBuf[stg][wave * 512]);
      dma16(Vh + kv2 + vLaneOff,      &vBuf[stg][wave * 512]);
      stg = (stg == 2) ? 0 : stg + 1;
    }

    ATTN_TILE(kBuf[cur], vBuf[cur]);
    cur = (cur == 2) ? 0 : cur + 1;
  }
  // peeled last tile (31): drain everything
  __builtin_amdgcn_sched_barrier(0);
  asm volatile("s_waitcnt vmcnt(0)" ::: "memory");
  __builtin_amdgcn_s_barrier();
  __builtin_amdgcn_sched_barrier(0);
  ATTN_TILE(kBuf[cur], vBuf[cur]);

#undef ATTN_TILE

#pragma unroll
  for (int m = 0; m < 2; m++) {
    ls[m] += __shfl_xor(ls[m], 16);
    ls[m] += __shfl_xor(ls[m], 32);
  }
#pragma unroll
  for (int m = 0; m < 2; m++) {
#pragma unroll
    for (int r = 0; r < 4; r++) {
      float l = __shfl(ls[m], (lane & 48) | (quad * 4 + r));
      float inv = 1.0f / l;
      int srow = q0 + m * 16 + quad * 4 + r;
      size_t base = ((size_t)b * S_ + srow) * (QH_ * HD_) + (size_t)qh * HD_;
#pragma unroll
      for (int t = 0; t < 4; t++)
        O[base + t * 16 + l16] = f2b(oacc[m][t][r] * inv);
    }
  }
}

// ---------------- launch ----------------

extern "C" void kernel_launch(void* const* d_in, const int* in_sizes, int n_in,
                              void* d_out, int out_size, void* d_ws, size_t ws_size,
                              hipStream_t stream) {
  const float* x  = (const float*)d_in[0];
  const float* fr = (const float*)d_in[1];
  const float* Wq = (const float*)d_in[2];
  const float* bq = (const float*)d_in[3];
  const float* Wk = (const float*)d_in[4];
  const float* bk = (const float*)d_in[5];
  const float* Wv = (const float*)d_in[6];
  const float* bv = (const float*)d_in[7];
  const float* Wo = (const float*)d_in[8];
  const float* bo = (const float*)d_in[9];
  float* out = (float*)d_out;
  char* ws = (char*)d_ws;

  ushort* xb    = (ushort*)(ws + 0);           // 16,777,216  x bf16 (reused as Ob)
  ushort* wqkv  = (ushort*)(ws + 16777216);    // 12,582,912
  ushort* wo    = (ushort*)(ws + 29360128);    //  8,388,608
  ushort* qb    = (ushort*)(ws + 37761024);    // 16,777,216  Q roped bf16 (perm d)
  ushort* kb    = (ushort*)(ws + 54538240);    //  4,194,304  K roped bf16 (perm d)
  ushort* vt    = (ushort*)(ws + 62926848);    //  4,194,304  V [d][s-perm] true-d
  ushort* ob    = xb;                          // alias: xb dead after gemm1

  conv_x_kernel<<<8192, 256, 0, stream>>>(x, xb);
  tconv_all_kernel<<<dim3(64, 64, 4), dim3(32, 8), 0, stream>>>(Wq, Wk, Wv, Wo, wqkv, wo);

  gemm_qkv_kernel<<<dim3(3072 / 256, 4096 / 256), 512, 0, stream>>>(
      xb, wqkv, bq, bk, bv, (const float2*)fr, qb, kb, vt);

  attn_kernel<<<dim3(8, 32, 2), 512, 0, stream>>>(qb, kb, vt, ob);

  gemm_bt_kernel<<<dim3(2048 / 128, 4096 / 128), 256, 0, stream>>>(
      ob, wo, bo, out, 4096, 2048, 2048);
}

// Round 9
// 291.754 us; speedup vs baseline: 1.1944x; 1.0373x over previous
//
#include <hip/hip_runtime.h>
#include <stdint.h>

#define B_   2
#define S_   2048
#define D_   2048
#define QH_  32
#define KVH_ 8
#define HD_  64

typedef short  short8  __attribute__((ext_vector_type(8)));
typedef float  floatx4 __attribute__((ext_vector_type(4)));

__device__ __forceinline__ ushort f2b(float f) {
  union { float f; uint32_t u; } c; c.f = f;
  uint32_t u = c.u;
  return (ushort)((u + 0x7FFFu + ((u >> 16) & 1u)) >> 16);
}

__device__ __forceinline__ uint32_t fbits(float f) {
  union { float f; uint32_t u; } c; c.f = f;
  return c.u;
}

__device__ __forceinline__ short8 mk8(uint32_t a, uint32_t b, uint32_t c, uint32_t d) {
  union { uint4 u; short8 s; } v; v.u = (uint4){a, b, c, d}; return v.s;
}

// packed bf16 convert: lo = bf16(a), hi = bf16(b).
__device__ __forceinline__ uint32_t cvtpk(float a, float b) {
  uint32_t r;
  asm("v_cvt_pk_bf16_f32 %0, %1, %2" : "=v"(r) : "v"(a), "v"(b));
  return r;
}

// async global->LDS DMA, 16B per lane. LDS dest = wave-uniform base + lane*16.
__device__ __forceinline__ void dma16(const void* g, void* l) {
  __builtin_amdgcn_global_load_lds(
      (const __attribute__((address_space(1))) uint32_t*)(uintptr_t)g,
      (__attribute__((address_space(3))) uint32_t*)(uintptr_t)l, 16, 0, 0);
}

#define QSCALE 0.18033688f   // 1/sqrt(64) * log2(e)

// ---------------- fused prep: weight transposes + x convert ----------------
// z<4: transpose+convert {Wq,Wk,Wv,Wo} [K][N] -> [N][K] bf16.
// z=4: x fp32 -> bf16 (8 elems/thread). One dispatch replaces two.

__global__ void prep_kernel(const float* __restrict__ Wq, const float* __restrict__ Wk,
                            const float* __restrict__ Wv, const float* __restrict__ Wo,
                            const float* __restrict__ X,
                            ushort* __restrict__ wqkv, ushort* __restrict__ wo,
                            ushort* __restrict__ Xb) {
  __shared__ float tile[32][33];
  int z = blockIdx.z;
  int tx = threadIdx.x, ty = threadIdx.y;
  if (z == 4) {
    int bid = blockIdx.y * 64 + blockIdx.x;
    int tid = ty * 32 + tx;
    size_t i = ((size_t)bid * 256 + tid) * 8;
    float4 v0 = *(const float4*)(X + i);
    float4 v1 = *(const float4*)(X + i + 4);
    ushort4 o0, o1;
    o0.x = f2b(v0.x); o0.y = f2b(v0.y); o0.z = f2b(v0.z); o0.w = f2b(v0.w);
    o1.x = f2b(v1.x); o1.y = f2b(v1.y); o1.z = f2b(v1.z); o1.w = f2b(v1.w);
    *(ushort4*)(Xb + i)     = o0;
    *(ushort4*)(Xb + i + 4) = o1;
    return;
  }
  const float* W; ushort* Wt; int N;
  if (z == 0)      { W = Wq; Wt = wqkv;                        N = 2048; }
  else if (z == 1) { W = Wk; Wt = wqkv + (size_t)2048 * 2048;  N = 512;  }
  else if (z == 2) { W = Wv; Wt = wqkv + (size_t)2560 * 2048;  N = 512;  }
  else             { W = Wo; Wt = wo;                          N = 2048; }
  int bx = blockIdx.x, by = blockIdx.y;
  if (bx * 32 >= N) return;
#pragma unroll
  for (int i = 0; i < 32; i += 8)
    tile[ty + i][tx] = W[(size_t)(by * 32 + ty + i) * N + bx * 32 + tx];
  __syncthreads();
#pragma unroll
  for (int i = 0; i < 32; i += 8)
    Wt[(size_t)(bx * 32 + ty + i) * 2048 + by * 32 + tx] = f2b(tile[tx][ty + i]);
}

// ---------------- fused QKV GEMM, 8-phase 256x256 schedule (r5 verified) ----
// BM=BN=256, BK=64, 8 waves (2M x 4N), 512 threads, 128 KiB LDS dbuf.
// Epilogue fuses bias (direct bq/bk/bv) and vpack (V -> Vt directly).
// NOTE r7 lesson: do NOT add a min-waves __launch_bounds__ here — forcing
// occupancy spilled acc[] to scratch (VGPR 48, WRITE_SIZE 5x, 123 us).

__global__ __launch_bounds__(512, 2) void gemm_qkv_kernel(
    const ushort* __restrict__ A, const ushort* __restrict__ Bt,
    const float* __restrict__ bq, const float* __restrict__ bk,
    const float* __restrict__ bv, const float2* __restrict__ F2,
    ushort* __restrict__ qb, ushort* __restrict__ kb, ushort* __restrict__ vt) {
  __shared__ ushort sA[2][256 * 64];
  __shared__ ushort sB[2][256 * 64];
  const int tid  = threadIdx.x;
  const int bm   = blockIdx.y, bn = blockIdx.x;
  const int wave = tid >> 6, lane = tid & 63;
  const int quad = lane >> 4, l16 = lane & 15;
  const int wm2  = wave >> 2, wn4 = wave & 3;
  const int sw7  = l16 & 7;
  const int dr   = lane >> 3, du = (lane & 7) ^ dr;
  const int srow = wave * 8 + dr;
  const int lcol = (lane & 7) * 8;

  const ushort* Ab = A  + (size_t)(bm * 256) * 2048;
  const ushort* Bb = Bt + (size_t)(bn * 256) * 2048;

  floatx4 acc[8][4];
#pragma unroll
  for (int i = 0; i < 8; i++)
#pragma unroll
    for (int j = 0; j < 4; j++) acc[i][j] = (floatx4){0.f, 0.f, 0.f, 0.f};

  short8 af[4][2], bf[4][2];

#define STG_A(t, h) do {                                                      \
    dma16(Ab + (size_t)((h)*128 +      srow) * 2048 + (size_t)(t)*64 + du*8,  \
          &sA[(t)&1][((h)*128 +      srow) * 64 + lcol]);                     \
    dma16(Ab + (size_t)((h)*128 + 64 + srow) * 2048 + (size_t)(t)*64 + du*8,  \
          &sA[(t)&1][((h)*128 + 64 + srow) * 64 + lcol]);                     \
  } while (0)

#define STG_B(t, h) do {                                                      \
    dma16(Bb + (size_t)((h)*128 +      srow) * 2048 + (size_t)(t)*64 + du*8,  \
          &sB[(t)&1][((h)*128 +      srow) * 64 + lcol]);                     \
    dma16(Bb + (size_t)((h)*128 + 64 + srow) * 2048 + (size_t)(t)*64 + du*8,  \
          &sB[(t)&1][((h)*128 + 64 + srow) * 64 + lcol]);                     \
  } while (0)

#define LDA(Sb, mh) do {                                                      \
    _Pragma("unroll") for (int mi2 = 0; mi2 < 4; mi2++) {                     \
      const int rr = ((mh)*128 + wm2*64 + mi2*16 + l16) * 64;                 \
      af[mi2][0] = *(const short8*)&(Sb)[rr + (((quad    ) ^ sw7) * 8)];      \
      af[mi2][1] = *(const short8*)&(Sb)[rr + (((quad + 4) ^ sw7) * 8)];      \
    } } while (0)

#define LDB(Sb, nh) do {                                                      \
    _Pragma("unroll") for (int ni2 = 0; ni2 < 2; ni2++) {                     \
      const int rr = ((nh)*128 + wn4*32 + ni2*16 + l16) * 64;                 \
      bf[(nh)*2+ni2][0] = *(const short8*)&(Sb)[rr + (((quad    ) ^ sw7) * 8)]; \
      bf[(nh)*2+ni2][1] = *(const short8*)&(Sb)[rr + (((quad + 4) ^ sw7) * 8)]; \
    } } while (0)

#define MFMA_PH(mh, nh) do {                                                  \
    __builtin_amdgcn_s_setprio(1);                                           \
    _Pragma("unroll") for (int mi2 = 0; mi2 < 4; mi2++)                       \
    _Pragma("unroll") for (int ni2 = 0; ni2 < 2; ni2++)                       \
    _Pragma("unroll") for (int ks = 0; ks < 2; ks++)                          \
      acc[(mh)*4+mi2][(nh)*2+ni2] = __builtin_amdgcn_mfma_f32_16x16x32_bf16(  \
        af[mi2][ks], bf[(nh)*2+ni2][ks], acc[(mh)*4+mi2][(nh)*2+ni2], 0,0,0); \
    __builtin_amdgcn_s_setprio(0);                                            \
  } while (0)

#define PH_SYNC() do {                                                        \
    __builtin_amdgcn_sched_barrier(0);                                        \
    __builtin_amdgcn_s_barrier();                                             \
    asm volatile("s_waitcnt lgkmcnt(0)" ::: "memory");                        \
    __builtin_amdgcn_sched_barrier(0);                                        \
  } while (0)

#define PH_END() do {                                                         \
    __builtin_amdgcn_sched_barrier(0);                                        \
    __builtin_amdgcn_s_barrier();                                             \
    __builtin_amdgcn_sched_barrier(0);                                        \
  } while (0)

  // ---- prologue: tile0 full + tile1 {hA0, hB0, hB1} (order matters) ----
  STG_A(0, 0); STG_A(0, 1); STG_B(0, 0); STG_B(0, 1);
  STG_A(1, 0); STG_B(1, 0); STG_B(1, 1);
  asm volatile("s_waitcnt vmcnt(6)" ::: "memory");
  __builtin_amdgcn_s_barrier();

#pragma unroll 1
  for (int i = 0; i < 16; ++i) {
    const int t0 = 2 * i, t1 = 2 * i + 1;
    const bool more = (i < 15);
    const ushort* A0 = sA[0]; const ushort* B0 = sB[0];
    const ushort* A1 = sA[1]; const ushort* B1 = sB[1];

    // phase 1: read B0[nh0] + A0[mh0]; stage hA1(t1)
    LDB(B0, 0); LDA(A0, 0);
    STG_A(t1, 1);
    PH_SYNC(); MFMA_PH(0, 0); PH_END();

    // phase 2: read B0[nh1]; stage hA0(t0+2)
    LDB(B0, 1);
    if (more) STG_A(t0 + 2, 0);
    PH_SYNC(); MFMA_PH(0, 1); PH_END();

    // phase 3: read A0[mh1]; stage hB0(t0+2)
    LDA(A0, 1);
    if (more) STG_B(t0 + 2, 0);
    PH_SYNC(); MFMA_PH(1, 0); PH_END();

    // phase 4: stage hB1(t0+2); vmcnt -> tile t1 landed
    if (more) STG_B(t0 + 2, 1);
    PH_SYNC(); MFMA_PH(1, 1);
    if (more) asm volatile("s_waitcnt vmcnt(6)" ::: "memory");
    else      asm volatile("s_waitcnt vmcnt(0)" ::: "memory");
    PH_END();

    // phase 5: read B1[nh0] + A1[mh0]; stage hA1(t0+2)
    LDB(B1, 0); LDA(A1, 0);
    if (more) STG_A(t0 + 2, 1);
    PH_SYNC(); MFMA_PH(0, 0); PH_END();

    // phase 6: read B1[nh1]; stage hA0(t1+2)
    LDB(B1, 1);
    if (more) STG_A(t1 + 2, 0);
    PH_SYNC(); MFMA_PH(0, 1); PH_END();

    // phase 7: read A1[mh1]; stage hB0(t1+2)
    LDA(A1, 1);
    if (more) STG_B(t1 + 2, 0);
    PH_SYNC(); MFMA_PH(1, 0); PH_END();

    // phase 8: stage hB1(t1+2); vmcnt -> tile t0+2 landed
    if (more) STG_B(t1 + 2, 1);
    PH_SYNC(); MFMA_PH(1, 1);
    if (more) asm volatile("s_waitcnt vmcnt(6)" ::: "memory");
    PH_END();
  }

#undef STG_A
#undef STG_B
#undef LDA
#undef LDB
#undef MFMA_PH
#undef PH_SYNC
#undef PH_END

  // ---- fused epilogue (bias + RoPE + permuted-d packed stores; V->Vt) ----
  const int isQ = (bn < 8);
  const int isV = (bn >= 10);
  const float sySign = (l16 & 1) ? 1.f : -1.f;

  const float* bsrc = isQ ? bq : (isV ? bv : bk);
  const int    boff = isQ ? 0  : (isV ? 2560 : 2048);

  float bvv[4];
#pragma unroll
  for (int ni = 0; ni < 4; ni++)
    bvv[ni] = bsrc[bn * 256 + (ni >> 1) * 128 + wn4 * 32 + (ni & 1) * 16 + l16 - boff];

  if (!isV) {
    ushort* dst = isQ ? qb : kb;
    const int NH   = isQ ? QH_ : KVH_;
    const int hoff = isQ ? 0 : 8;
    const int dpb  = l16 * 4 + (wn4 & 1) * 2;
#pragma unroll
    for (int mi = 0; mi < 8; mi++) {
#pragma unroll
      for (int r = 0; r < 4; r++) {
        int row = bm * 256 + (mi >> 2) * 128 + wm2 * 64 + (mi & 3) * 16 + quad * 4 + r;
        int s = row & 2047, bb = row >> 11;
        float o[4];
#pragma unroll
        for (int ni = 0; ni < 4; ni++) {
          float xv = acc[mi][ni][r] + bvv[ni];
          float2 cs = F2[s * 32 + (wn4 & 1) * 16 + (ni & 1) * 8 + (l16 >> 1)];
          float pp = __shfl_xor(xv, 1);
          float oo = fmaf(pp * sySign, cs.y, xv * cs.x);
          if (isQ) oo *= QSCALE;
          o[ni] = oo;
        }
#pragma unroll
        for (int hh = 0; hh < 2; hh++) {
          int h = (bn - hoff) * 4 + hh * 2 + (wn4 >> 1);
          size_t base = (((size_t)bb * NH + h) * S_ + s) * HD_ + dpb;
          ushort2 st; st.x = f2b(o[hh * 2 + 0]); st.y = f2b(o[hh * 2 + 1]);
          *(ushort2*)&dst[base] = st;
        }
      }
    }
  } else {
    // V: write directly into Vt [bb*8+h][64 d][2048 pos] (vpack fused).
#pragma unroll
    for (int mi = 0; mi < 8; mi++) {
      int row0 = bm * 256 + (mi >> 2) * 128 + wm2 * 64 + (mi & 3) * 16 + quad * 4;
      int bb   = row0 >> 11;
      int posb = ((row0 & 2047) & ~63) + (mi & 2) * 16 + quad * 8 + (mi & 1) * 4;
#pragma unroll
      for (int ni = 0; ni < 4; ni++) {
        int h  = (bn - 10) * 4 + (ni >> 1) * 2 + (wn4 >> 1);
        int dt = (wn4 & 1) * 32 + (ni & 1) * 16 + l16;
        ushort4 st;
        st.x = f2b(acc[mi][ni][0] + bvv[ni]);
        st.y = f2b(acc[mi][ni][1] + bvv[ni]);
        st.z = f2b(acc[mi][ni][2] + bvv[ni]);
        st.w = f2b(acc[mi][ni][3] + bvv[ni]);
        *(ushort4*)&vt[(((size_t)bb * 8 + h) * 64 + dt) * (size_t)S_ + posb] = st;
      }
    }
  }
}

// ---------------- GEMM: C[M][N] = A @ Bt^T + bias (fp32 out) ----------------
// Linear block mapping: xcd = wg%8 = bn%8 naturally gives each XCD a fixed
// 2-column B slice (2MB, L2-resident, 32x reuse). Do NOT swizzle (r7 lesson).

__global__ __launch_bounds__(256) void gemm_bt_kernel(
    const ushort* __restrict__ A, const ushort* __restrict__ Bt,
    const float* __restrict__ bias, float* __restrict__ C,
    int M, int N, int K) {
  __shared__ ushort sA[2][128 * 32];
  __shared__ ushort sB[2][128 * 32];
  const int tid  = threadIdx.x;
  const int bm   = blockIdx.y, bn = blockIdx.x;
  const int wave = tid >> 6, lane = tid & 63;
  const int quad = lane >> 4, l16 = lane & 15;
  const int wm   = (wave >> 1) * 64, wn = (wave & 1) * 64;

  const ushort* Ab = A  + (size_t)(bm * 128) * K;
  const ushort* Bb = Bt + (size_t)(bn * 128) * K;

  const int gr = lane >> 2;
  const int gu = (lane & 3) * 8;

  floatx4 acc[4][4];
#pragma unroll
  for (int i = 0; i < 4; i++)
#pragma unroll
    for (int j = 0; j < 4; j++) acc[i][j] = (floatx4){0.f, 0.f, 0.f, 0.f};

#pragma unroll
  for (int j = 0; j < 2; j++) {
    int row = j * 64 + wave * 16 + gr;
    dma16(Ab + (size_t)row * K + gu, &sA[0][j * 2048 + wave * 512]);
    dma16(Bb + (size_t)row * K + gu, &sB[0][j * 2048 + wave * 512]);
  }

  int cur = 0;
  for (int k0 = 0; k0 < K; k0 += 32) {
    __syncthreads();
    if (k0 + 32 < K) {
      int nxt = cur ^ 1;
#pragma unroll
      for (int j = 0; j < 2; j++) {
        int row = j * 64 + wave * 16 + gr;
        dma16(Ab + (size_t)row * K + k0 + 32 + gu, &sA[nxt][j * 2048 + wave * 512]);
        dma16(Bb + (size_t)row * K + k0 + 32 + gu, &sB[nxt][j * 2048 + wave * 512]);
      }
    }
    short8 af[4], bf[4];
#pragma unroll
    for (int mi = 0; mi < 4; mi++)
      af[mi] = *(const short8*)&sA[cur][(wm + mi * 16 + l16) * 32 + quad * 8];
#pragma unroll
    for (int ni = 0; ni < 4; ni++)
      bf[ni] = *(const short8*)&sB[cur][(wn + ni * 16 + l16) * 32 + quad * 8];
#pragma unroll
    for (int mi = 0; mi < 4; mi++)
#pragma unroll
      for (int ni = 0; ni < 4; ni++)
        acc[mi][ni] = __builtin_amdgcn_mfma_f32_16x16x32_bf16(
            af[mi], bf[ni], acc[mi][ni], 0, 0, 0);
    cur ^= 1;
  }

#pragma unroll
  for (int mi = 0; mi < 4; mi++) {
#pragma unroll
    for (int ni = 0; ni < 4; ni++) {
      int col  = bn * 128 + wn + ni * 16 + l16;
      float bv = bias[col];
#pragma unroll
      for (int r = 0; r < 4; r++) {
        int row = bm * 128 + wm + mi * 16 + quad * 4 + r;
        C[(size_t)row * N + col] = acc[mi][ni][r] + bv;
      }
    }
  }
}

// ---------------- Flash attention (register P, no LDS round-trip) ----------
// grid flat 512 blocks, block 512 (8 waves), 2 blocks/CU (4 waves/SIMD).
// Block-id remap clusters all 32 blocks sharing one (b,kvh)'s K/V onto one
// XCD: id = kvh + 8*qt + 64*g + 256*b.
// r8: 3-buffer ring + counted vmcnt (issue 2 tiles ahead, drain vmcnt(2)).
// r9: softmax denominator via ones-B MFMA — lsa[m] = mfma(ap[m], ones, lsa)
// gives D[q][*] = rowsum(P) with q = quad*4+r, replacing 24 serial VALU adds
// per tile and the end-of-kernel shuffle reduce (MFMA pipe has headroom;
// VALU is the busier pipe per rocprof).

__global__ __launch_bounds__(512, 4) void attn_kernel(
    const ushort* __restrict__ Q, const ushort* __restrict__ K,
    const ushort* __restrict__ Vt, ushort* __restrict__ O) {
  const int id  = blockIdx.x + 8 * (blockIdx.y + 32 * blockIdx.z);
  const int kvh = id & 7;
  const int qt  = (id >> 3) & 7;
  const int qh  = kvh * 4 + ((id >> 6) & 3);
  const int b   = id >> 8;
  const int tid = threadIdx.x;
  const int wave = tid >> 6, lane = tid & 63;
  const int quad = lane >> 4, l16 = lane & 15;

  __shared__ ushort kBuf[3][64 * 64];   // 24 KB
  __shared__ ushort vBuf[3][64 * 64];   // 24 KB

  const ushort* Qh = Q  + ((size_t)(b * QH_ + qh)) * S_ * HD_;
  const ushort* Kh = K  + ((size_t)(b * KVH_ + kvh)) * S_ * HD_;
  const ushort* Vh = Vt + ((size_t)(b * KVH_ + kvh)) * HD_ * S_;

  const int dr = lane >> 3;
  const int du = (lane & 7) ^ (dr & 7);
  const size_t kLaneOff = (size_t)(wave * 8 + dr) * 64 + du * 8;
  const size_t vLaneOff = (size_t)(wave * 8 + dr) * S_ + du * 8;
  const int swz = l16 & 7;

  const int q0 = qt * 256 + wave * 32;
  short8 aq[2][2];
#pragma unroll
  for (int m = 0; m < 2; m++)
#pragma unroll
    for (int s2 = 0; s2 < 2; s2++)
      aq[m][s2] = *(const short8*)(Qh + (size_t)(q0 + m * 16 + l16) * HD_ + s2 * 32 + quad * 8);

  floatx4 oacc[2][4];
#pragma unroll
  for (int m = 0; m < 2; m++)
#pragma unroll
    for (int t = 0; t < 4; t++) oacc[m][t] = (floatx4){0.f, 0.f, 0.f, 0.f};
  // softmax denominators: lsa[m][r] = rowsum(P) for q = quad*4+r (ones-B MFMA)
  floatx4 lsa[2];
  lsa[0] = (floatx4){0.f, 0.f, 0.f, 0.f};
  lsa[1] = (floatx4){0.f, 0.f, 0.f, 0.f};
  const short8 vone = mk8(0x3F803F80u, 0x3F803F80u, 0x3F803F80u, 0x3F803F80u);

  // prologue: stage tiles 0 and 1 (2 dma16/wave each)
  dma16(Kh + kLaneOff, &kBuf[0][wave * 512]);
  dma16(Vh + vLaneOff, &vBuf[0][wave * 512]);
  dma16(Kh + (size_t)64 * 64 + kLaneOff, &kBuf[1][wave * 512]);
  dma16(Vh + 64 + vLaneOff,              &vBuf[1][wave * 512]);

#define ATTN_TILE(KB, VB)                                                     \
  do {                                                                        \
    _Pragma("unroll")                                                         \
    for (int u = 0; u < 2; u++) {                                             \
      uint32_t pk[2][4];                                                      \
      _Pragma("unroll")                                                       \
      for (int cc = 0; cc < 2; cc++) {                                        \
        const int c = u * 2 + cc;                                             \
        short8 kf0 = *(const short8*)&(KB)[(c * 16 + l16) * 64 + ((quad ^ swz) * 8)];        \
        short8 kf1 = *(const short8*)&(KB)[(c * 16 + l16) * 64 + (((4 + quad) ^ swz) * 8)];  \
        _Pragma("unroll")                                                     \
        for (int m = 0; m < 2; m++) {                                         \
          floatx4 sc = (floatx4){0.f, 0.f, 0.f, 0.f};                         \
          __builtin_amdgcn_s_setprio(1);                                      \
          sc = __builtin_amdgcn_mfma_f32_16x16x32_bf16(kf0, aq[m][0], sc, 0, 0, 0); \
          sc = __builtin_amdgcn_mfma_f32_16x16x32_bf16(kf1, aq[m][1], sc, 0, 0, 0); \
          __builtin_amdgcn_s_setprio(0);                                      \
          float p0 = __builtin_amdgcn_exp2f(sc[0]);                           \
          float p1 = __builtin_amdgcn_exp2f(sc[1]);                           \
          float p2 = __builtin_amdgcn_exp2f(sc[2]);                           \
          float p3 = __builtin_amdgcn_exp2f(sc[3]);                           \
          pk[m][cc * 2 + 0] = cvtpk(p0, p1);                                  \
          pk[m][cc * 2 + 1] = cvtpk(p2, p3);                                  \
        }                                                                     \
      }                                                                       \
      short8 ap0 = mk8(pk[0][0], pk[0][1], pk[0][2], pk[0][3]);               \
      short8 ap1 = mk8(pk[1][0], pk[1][1], pk[1][2], pk[1][3]);               \
      lsa[0] = __builtin_amdgcn_mfma_f32_16x16x32_bf16(ap0, vone, lsa[0], 0, 0, 0); \
      lsa[1] = __builtin_amdgcn_mfma_f32_16x16x32_bf16(ap1, vone, lsa[1], 0, 0, 0); \
      _Pragma("unroll")                                                       \
      for (int t = 0; t < 4; t++) {                                           \
        const int row = (t * 16 + l16) * 64;                                  \
        short8 vf = *(const short8*)&(VB)[row + (((u * 4 + quad) ^ swz) * 8)]; \
        __builtin_amdgcn_s_setprio(1);                                        \
        oacc[0][t] = __builtin_amdgcn_mfma_f32_16x16x32_bf16(ap0, vf, oacc[0][t], 0, 0, 0); \
        oacc[1][t] = __builtin_amdgcn_mfma_f32_16x16x32_bf16(ap1, vf, oacc[1][t], 0, 0, 0); \
        __builtin_amdgcn_s_setprio(0);                                        \
      }                                                                       \
    }                                                                         \
  } while (0)

  int cur = 0, stg = 2;
#pragma unroll 1
  for (int i = 0; i < 31; ++i) {
    // drain tile i (leave tile i+1 in flight), then sync
    __builtin_amdgcn_sched_barrier(0);
    asm volatile("s_waitcnt vmcnt(2)" ::: "memory");
    __builtin_amdgcn_s_barrier();
    __builtin_amdgcn_sched_barrier(0);

    if (i <= 29) {
      size_t kv2 = (size_t)(i + 2) * 64;
      dma16(Kh + kv2 * 64 + kLaneOff, &kBuf[stg][wave * 512]);
      dma16(Vh + kv2 + vLaneOff,      &vBuf[stg][wave * 512]);
      stg = (stg == 2) ? 0 : stg + 1;
    }

    ATTN_TILE(kBuf[cur], vBuf[cur]);
    cur = (cur == 2) ? 0 : cur + 1;
  }
  // peeled last tile (31): drain everything
  __builtin_amdgcn_sched_barrier(0);
  asm volatile("s_waitcnt vmcnt(0)" ::: "memory");
  __builtin_amdgcn_s_barrier();
  __builtin_amdgcn_sched_barrier(0);
  ATTN_TILE(kBuf[cur], vBuf[cur]);

#undef ATTN_TILE

#pragma unroll
  for (int m = 0; m < 2; m++) {
#pragma unroll
    for (int r = 0; r < 4; r++) {
      float inv = 1.0f / lsa[m][r];
      int srow = q0 + m * 16 + quad * 4 + r;
      size_t base = ((size_t)b * S_ + srow) * (QH_ * HD_) + (size_t)qh * HD_;
#pragma unroll
      for (int t = 0; t < 4; t++)
        O[base + t * 16 + l16] = f2b(oacc[m][t][r] * inv);
    }
  }
}

// ---------------- launch ----------------

extern "C" void kernel_launch(void* const* d_in, const int* in_sizes, int n_in,
                              void* d_out, int out_size, void* d_ws, size_t ws_size,
                              hipStream_t stream) {
  const float* x  = (const float*)d_in[0];
  const float* fr = (const float*)d_in[1];
  const float* Wq = (const float*)d_in[2];
  const float* bq = (const float*)d_in[3];
  const float* Wk = (const float*)d_in[4];
  const float* bk = (const float*)d_in[5];
  const float* Wv = (const float*)d_in[6];
  const float* bv = (const float*)d_in[7];
  const float* Wo = (const float*)d_in[8];
  const float* bo = (const float*)d_in[9];
  float* out = (float*)d_out;
  char* ws = (char*)d_ws;

  ushort* xb    = (ushort*)(ws + 0);           // 16,777,216  x bf16 (reused as Ob)
  ushort* wqkv  = (ushort*)(ws + 16777216);    // 12,582,912
  ushort* wo    = (ushort*)(ws + 29360128);    //  8,388,608
  ushort* qb    = (ushort*)(ws + 37761024);    // 16,777,216  Q roped bf16 (perm d)
  ushort* kb    = (ushort*)(ws + 54538240);    //  4,194,304  K roped bf16 (perm d)
  ushort* vt    = (ushort*)(ws + 62926848);    //  4,194,304  V [d][s-perm] true-d
  ushort* ob    = xb;                          // alias: xb dead after gemm1

  prep_kernel<<<dim3(64, 64, 5), dim3(32, 8), 0, stream>>>(
      Wq, Wk, Wv, Wo, x, wqkv, wo, xb);

  gemm_qkv_kernel<<<dim3(3072 / 256, 4096 / 256), 512, 0, stream>>>(
      xb, wqkv, bq, bk, bv, (const float2*)fr, qb, kb, vt);

  attn_kernel<<<dim3(8, 32, 2), 512, 0, stream>>>(qb, kb, vt, ob);

  gemm_bt_kernel<<<dim3(2048 / 128, 4096 / 128), 256, 0, stream>>>(
      ob, wo, bo, out, 4096, 2048, 2048);
}